// Round 24
// baseline (154.184 us; speedup 1.0000x reference)
//
#include <hip/hip_runtime.h>

// EncoderTreeRNN — R24: R22 exact fused (best wall 128.5) + T14-pipelined h1tab
// (2 tiles/block: tile1 gather in flight under tile0 compute).
// Tree (word=0): z=sigm(hl Uzl+hr Uzr+bz), r=sigm(hl Url+hr Urr+br),
//                h~=tanh((r*hl)Uhl+(r*hr)Uhr+bh), out=z*(hl+hr)+(1-z)*h~
// z/r weights+biases pre-scaled by log2e -> z = rcp(1+exp2(-x')); h by 2*log2e.
// K interleaved (k'=2j -> hl[j], 2j+1 -> hr[j]); U rows permuted to match.
// U frag (16x16): Uf[((w*8+ks)*64+l)*8+j] = U'[ks*32+(l>>4)*8+j][w*16+(l&15)].
// C/D (16x16): col=lane&15, row=(lane>>4)*4+q.

typedef _Float16 half_t;
typedef __attribute__((ext_vector_type(8))) _Float16 f16x8;
typedef __attribute__((ext_vector_type(4))) float f32x4;

#define NTOK 262144
#define NB 4096
#define NV 100000
#define C1 1.4426950408889634f   // log2(e)
#define C2 2.8853900817779268f   // 2*log2(e)
#define LS 272                   // LDS row stride (halves): 136 dw === 8 mod 32

__device__ __forceinline__ float sigm2(float x){   // x pre-scaled by log2e
  return __builtin_amdgcn_rcpf(1.0f + __builtin_amdgcn_exp2f(-x));
}
__device__ __forceinline__ float tanh2(float y){   // y pre-scaled by 2*log2e
  float r = __builtin_amdgcn_rcpf(1.0f + __builtin_amdgcn_exp2f(y));
  return __builtin_fmaf(-2.0f, r, 1.0f);
}

// Fragment-contiguous PRE-SCALED weights + combined pre-scaled biases (block 511).
__global__ __launch_bounds__(256) void wprep_k(
    const float* Wz, const float* Wh,
    const float* Uzl,const float* Uzr,const float* Url,const float* Urr,
    const float* Uhl,const float* Uhr,
    const float* bWz,const float* bUzl,const float* bUzr,
    const float* bWr,const float* bUrl,const float* bUrr,
    const float* bWh,const float* bUhl,const float* bUhr,
    half_t* wb, float* bc){
  int idx = blockIdx.x*256 + threadIdx.x;           // 131072 total
  if (idx < 32768){                                  // Wz_f (x C1), Wh_f (x C2)
    const float* W = (idx < 16384) ? Wz : Wh;
    float sc = (idx < 16384) ? C1 : C2;
    int t = idx & 16383;
    int w = t >> 11, ks = (t >> 9) & 3, l = (t >> 3) & 63, j = t & 7;
    int n = w*16 + (l & 15);
    int k = ks*32 + ((l >> 4) << 3) + j;
    wb[idx] = (half_t)(W[k*128 + n] * sc);
  } else {                                           // Uz_f(C1), Ur_f(C1), Uh_f(C2)
    int t = idx - 32768;
    int mat = t >> 15;                               // 0=z,1=r,2=h
    t &= 32767;
    int w = t >> 12, ks = (t >> 9) & 7, l = (t >> 3) & 63, j = t & 7;
    int n = w*16 + (l & 15);
    int kp = ks*32 + ((l >> 4) << 3) + j;            // 0..255 interleaved
    int k = kp >> 1;
    const float* U;
    if (mat == 0) U = (kp & 1) ? Uzr : Uzl;
    else if (mat == 1) U = (kp & 1) ? Urr : Url;
    else U = (kp & 1) ? Uhr : Uhl;
    float sc = (mat == 2) ? C2 : C1;
    wb[idx] = (half_t)(U[k*128 + n] * sc);
  }
  if (blockIdx.x == 511 && threadIdx.x < 128){
    int j = threadIdx.x;
    bc[j]       = (bWz[j] + bUzl[j] + bUzr[j]) * C1;
    bc[128 + j] = (bWr[j] + bUrl[j] + bUrr[j]) * C1;
    bc[256 + j] = (bWh[j] + bUhl[j] + bUhr[j]) * C2;
  }
}

// Vocab table, T14-pipelined: 2 tiles of 64 rows per block; tile1 loads issued
// before tile0's compute. No hA analog: sequential coalesced fp32 reads.
__global__ __launch_bounds__(512, 8) void h1tab_k(
    const float* __restrict__ emb,
    const half_t* __restrict__ Wz_f, const half_t* __restrict__ Wh_f,
    const float* __restrict__ bc, half_t* __restrict__ t1)
{
  __shared__ __align__(16) _Float16 xs[2][64][144];   // 2 x 18.4 KB; 72 dw === 8 mod 32
  const int tid = threadIdx.x;
  const int m0  = blockIdx.x*128;
  const int w = tid>>6, l = tid&63;
  const int lr = l&15, lk = (l>>4)*8, lq = (l>>4)*4;
  const int col = w*16 + lr;
  const float bzv = bc[col], bhv = bc[256+col];
  const half_t* wzp = Wz_f + ((w*4)*64 + l)*8;
  const half_t* whp = Wh_f + ((w*4)*64 + l)*8;

  float4 stg[2][4];
  auto gload = [&](int t){
    #pragma unroll
    for (int it = 0; it < 4; it++){
      int idx = it*512 + tid;                // 64 rows x 32 float4-chunks
      int m = idx >> 5, c = idx & 31;
      int row = m0 + t*64 + m; if (row >= NV) row = 0;
      stg[t][it] = ((const float4*)(emb + (size_t)row*128))[c];
    }
  };
  auto gwrite = [&](int t){
    #pragma unroll
    for (int it = 0; it < 4; it++){
      int idx = it*512 + tid;
      int m = idx >> 5, c = idx & 31;
      float4 v = stg[t][it];
      union { half_t h[4]; ushort4 u; } p;
      p.h[0]=(half_t)v.x; p.h[1]=(half_t)v.y; p.h[2]=(half_t)v.z; p.h[3]=(half_t)v.w;
      *(ushort4*)&xs[t][m][c*4] = p.u;
    }
  };
  auto compute = [&](int t){
    f32x4 zacc[4] = {}; f32x4 hacc[4] = {};
    #pragma unroll
    for (int ks=0; ks<4; ks++){
      f16x8 bz = *(const f16x8*)(wzp + ks*512);
      f16x8 bh = *(const f16x8*)(whp + ks*512);
      #pragma unroll
      for (int mt=0; mt<4; mt++){
        f16x8 a = *(const f16x8*)&xs[t][mt*16 + lr][ks*32 + lk];
        zacc[mt] = __builtin_amdgcn_mfma_f32_16x16x32_f16(a, bz, zacc[mt],0,0,0);
        hacc[mt] = __builtin_amdgcn_mfma_f32_16x16x32_f16(a, bh, hacc[mt],0,0,0);
      }
    }
    #pragma unroll
    for (int mt=0; mt<4; mt++){
      #pragma unroll
      for (int q=0; q<4; q++){
        int row = m0 + t*64 + mt*16 + lq + q;
        if (row < NV){
          float z  = sigm2(zacc[mt][q] + bzv);
          float ht = tanh2(hacc[mt][q] + bhv);
          t1[(size_t)row*128 + col] = (half_t)((1.f-z)*ht);
        }
      }
    }
  };

  gload(0);
  gwrite(0);
  gload(1);                 // T14: in flight under tile0 compute
  __syncthreads();
  compute(0);
  gwrite(1);
  __syncthreads();
  compute(1);
}

// One tree level on LDS. X: input slots (interleaved {hl,hr}), Y: next-level input slots.
// RV = valid out rows (<= MT*16); slot0 = Y slot offset; LAST: write f32 to outf.
template<int MT, int RV, int LAST>
static __device__ __forceinline__ void level_step(
    _Float16 (*X)[LS], _Float16 (*Y)[LS], int tid,
    const half_t* Uz_f, const half_t* Ur_f, const half_t* Uh_f,
    const float* bc, float* outf, int outrow0, int slot0)
{
  const int w = tid>>6, l = tid&63;
  const int lr = l&15, lk = (l>>4)*8, lq = (l>>4)*4;
  const int col = w*16 + lr;

  f32x4 zacc[MT] = {}, racc[MT] = {};
  const half_t* uzp = Uz_f + ((w*8)*64 + l)*8;
  const half_t* urp = Ur_f + ((w*8)*64 + l)*8;
  #pragma unroll
  for (int ks=0; ks<8; ks++){
    f16x8 bz = *(const f16x8*)(uzp + ks*512);
    f16x8 br = *(const f16x8*)(urp + ks*512);
    #pragma unroll
    for (int mt=0; mt<MT; mt++){
      f16x8 a = *(const f16x8*)&X[mt*16 + lr][ks*32 + lk];
      zacc[mt] = __builtin_amdgcn_mfma_f32_16x16x32_f16(a, bz, zacc[mt],0,0,0);
      racc[mt] = __builtin_amdgcn_mfma_f32_16x16x32_f16(a, br, racc[mt],0,0,0);
    }
  }
  __syncthreads();

  uint zp[MT][2], sp[MT][2];
  const float bzv = bc[col], brv = bc[128+col];
  #pragma unroll
  for (int mt=0; mt<MT; mt++){
    union { half_t h[4]; uint u[2]; } pz, ps;
    #pragma unroll
    for (int q=0; q<4; q++){
      int row = mt*16 + lq + q;
      union { uint u; half_t h[2]; } io;
      io.u = *(uint*)&X[row][2*col];
      float hl = (float)io.h[0];
      float hr = (float)io.h[1];
      float z  = sigm2(zacc[mt][q] + bzv);
      float rv = sigm2(racc[mt][q] + brv);
      pz.h[q] = (half_t)z;
      ps.h[q] = (half_t)(hl + hr);
      io.h[0] = (half_t)(rv*hl);
      io.h[1] = (half_t)(rv*hr);
      *(uint*)&X[row][2*col] = io.u;
    }
    zp[mt][0]=pz.u[0]; zp[mt][1]=pz.u[1];
    sp[mt][0]=ps.u[0]; sp[mt][1]=ps.u[1];
  }
  __syncthreads();

  f32x4 ha[MT] = {};
  const half_t* uhp = Uh_f + ((w*8)*64 + l)*8;
  #pragma unroll
  for (int ks=0; ks<8; ks++){
    f16x8 bh = *(const f16x8*)(uhp + ks*512);
    #pragma unroll
    for (int mt=0; mt<MT; mt++){
      f16x8 a = *(const f16x8*)&X[mt*16 + lr][ks*32 + lk];
      ha[mt] = __builtin_amdgcn_mfma_f32_16x16x32_f16(a, bh, ha[mt],0,0,0);
    }
  }
  const float bhv = bc[256+col];
  #pragma unroll
  for (int mt=0; mt<MT; mt++){
    union { half_t h[4]; uint u[2]; } pz, ps;
    pz.u[0]=zp[mt][0]; pz.u[1]=zp[mt][1];
    ps.u[0]=sp[mt][0]; ps.u[1]=sp[mt][1];
    #pragma unroll
    for (int q=0; q<4; q++){
      int row = mt*16 + lq + q;
      if (row < RV){
        float ht = tanh2(ha[mt][q] + bhv);
        float z  = (float)pz.h[q];
        float o  = z*(float)ps.h[q] + (1.f-z)*ht;
        if (LAST) outf[(size_t)(outrow0 + row)*128 + col] = o;
        else      Y[slot0 + (row>>1)][2*col + (row&1)] = (half_t)o;
      }
    }
  }
  __syncthreads();
}

// Fused L1..L6: block g = batches 4g..4g+3 (tokens 256g..+255, L1 out rows 128g..+127).
// T14: chunk1's gather loads issued before chunk0's level_step; written after it.
__global__ __launch_bounds__(512, 2) void fused_k(
    const half_t* __restrict__ t1, const int* __restrict__ tokens,
    float* __restrict__ outf,
    const half_t* __restrict__ Uz_f, const half_t* __restrict__ Ur_f, const half_t* __restrict__ Uh_f,
    const float* __restrict__ bc)
{
  __shared__ __align__(16) _Float16 XA[64][LS];   // 34.8 KB
  __shared__ __align__(16) _Float16 XB[64][LS];   // 34.8 KB
  const int tid = threadIdx.x;
  const int g = blockIdx.x;

  uint2 sA[2][4], sB[2][4];
  auto gload = [&](int k){
    #pragma unroll
    for (int it = 0; it < 4; it++){
      int idx = it*512 + tid;           // 64 rows x 32 chunks
      int m = idx >> 5, c = idx & 31;
      int gm = 128*g + 64*k + m;        // global L1 out row
      int tl = tokens[2*gm], tr = tokens[2*gm+1];
      sA[k][it] = *(const uint2*)(t1 + (size_t)tl*128 + c*4);
      sB[k][it] = *(const uint2*)(t1 + (size_t)tr*128 + c*4);
    }
  };
  auto gwrite = [&](int k){
    #pragma unroll
    for (int it = 0; it < 4; it++){
      int idx = it*512 + tid;
      int m = idx >> 5, c = idx & 31;
      uint2 A = sA[k][it], Bv = sB[k][it];
      uint4 o;
      o.x = (A.x & 0xFFFFu) | (Bv.x << 16);
      o.y = (A.x >> 16)     | (Bv.x & 0xFFFF0000u);
      o.z = (A.y & 0xFFFFu) | (Bv.y << 16);
      o.w = (A.y >> 16)     | (Bv.y & 0xFFFF0000u);
      *(uint4*)&XA[m][c*8] = o;
    }
  };

  // ---- L1, two chunks; chunk1 loads in flight during chunk0's level_step ----
  gload(0);
  gwrite(0);
  gload(1);                     // T14: issue now, consume after chunk0
  __syncthreads();
  level_step<4,64,0>(XA, XB, tid, Uz_f, Ur_f, Uh_f, bc, outf, 0, 0);   // chunk0 -> XB 0..31
  gwrite(1);                    // XA free after level_step's trailing sync
  __syncthreads();
  level_step<4,64,0>(XA, XB, tid, Uz_f, Ur_f, Uh_f, bc, outf, 0, 32);  // chunk1 -> XB 32..63

  // ---- L2..L6 in LDS ----
  level_step<4,64,0>(XB, XA, tid, Uz_f, Ur_f, Uh_f, bc, outf, 0, 0);   // L2: 64 out -> XA 0..31
  level_step<2,32,0>(XA, XB, tid, Uz_f, Ur_f, Uh_f, bc, outf, 0, 0);   // L3: 32 out -> XB 0..15
  level_step<1,16,0>(XB, XA, tid, Uz_f, Ur_f, Uh_f, bc, outf, 0, 0);   // L4: 16 out -> XA 0..7
  level_step<1, 8,0>(XA, XB, tid, Uz_f, Ur_f, Uh_f, bc, outf, 0, 0);   // L5:  8 out -> XB 0..3
  level_step<1, 4,1>(XB, XA, tid, Uz_f, Ur_f, Uh_f, bc, outf, 4*g, 0); // L6:  4 out -> f32
}

extern "C" void kernel_launch(void* const* d_in, const int* in_sizes, int n_in,
                              void* d_out, int out_size, void* d_ws, size_t ws_size,
                              hipStream_t stream) {
  const int*   tokens = (const int*)  d_in[0];
  const float* emb    = (const float*)d_in[1];
  const float* Wz  = (const float*)d_in[2];  const float* bWz  = (const float*)d_in[3];
  const float* Uzl = (const float*)d_in[4];  const float* bUzl = (const float*)d_in[5];
  const float* Uzr = (const float*)d_in[6];  const float* bUzr = (const float*)d_in[7];
  const float* Wr  = (const float*)d_in[8];  const float* bWr  = (const float*)d_in[9];
  const float* Url = (const float*)d_in[10]; const float* bUrl = (const float*)d_in[11];
  const float* Urr = (const float*)d_in[12]; const float* bUrr = (const float*)d_in[13];
  const float* Wh  = (const float*)d_in[14]; const float* bWh  = (const float*)d_in[15];
  const float* Uhl = (const float*)d_in[16]; const float* bUhl = (const float*)d_in[17];
  const float* Uhr = (const float*)d_in[18]; const float* bUhr = (const float*)d_in[19];

  float*  bc = (float*)d_ws;
  half_t* wb = (half_t*)((char*)d_ws + 4096);
  half_t* Wz_f = wb;
  half_t* Wh_f = wb + 16384;
  half_t* Uz_f = wb + 32768;
  half_t* Ur_f = wb + 65536;
  half_t* Uh_f = wb + 98304;
  half_t* t1 = (half_t*)((char*)d_ws + (1<<20));     // 100000*128 f16 = 25.6 MB

  wprep_k<<<512, 256, 0, stream>>>(Wz,Wh,Uzl,Uzr,Url,Urr,Uhl,Uhr,
                                   bWz,bUzl,bUzr,bWr,bUrl,bUrr,bWh,bUhl,bUhr, wb, bc);

  h1tab_k<<<(NV + 127)/128, 512, 0, stream>>>(emb, Wz_f, Wh_f, bc, t1);

  // All 6 tree levels fused: 1024 blocks x 4 batches
  fused_k<<<1024, 512, 0, stream>>>(t1, tokens, (float*)d_out, Uz_f, Ur_f, Uh_f, bc);
}

// Round 25
// 128.319 us; speedup vs baseline: 1.2016x; 1.2016x over previous
//
#include <hip/hip_runtime.h>

// EncoderTreeRNN — R25: revert to R22 exactly (best verified wall 128.5 us).
// h1tab vocab table + fully-fused L1..L6 tree (in-LDS level chain), T14 async gather,
// exp2-domain activations, conflict-free LDS strides.
// Tree (word=0): z=sigm(hl Uzl+hr Uzr+bz), r=sigm(hl Url+hr Urr+br),
//                h~=tanh((r*hl)Uhl+(r*hr)Uhr+bh), out=z*(hl+hr)+(1-z)*h~
// z/r weights+biases pre-scaled by log2e -> z = rcp(1+exp2(-x')); h by 2*log2e.
// K interleaved (k'=2j -> hl[j], 2j+1 -> hr[j]); U rows permuted to match.
// U frag (16x16): Uf[((w*8+ks)*64+l)*8+j] = U'[ks*32+(l>>4)*8+j][w*16+(l&15)].
// C/D (16x16): col=lane&15, row=(lane>>4)*4+q.

typedef _Float16 half_t;
typedef __attribute__((ext_vector_type(8))) _Float16 f16x8;
typedef __attribute__((ext_vector_type(4))) float f32x4;

#define NTOK 262144
#define NB 4096
#define NV 100000
#define C1 1.4426950408889634f   // log2(e)
#define C2 2.8853900817779268f   // 2*log2(e)
#define LS 272                   // LDS row stride (halves): 136 dw === 8 mod 32

__device__ __forceinline__ float sigm2(float x){   // x pre-scaled by log2e
  return __builtin_amdgcn_rcpf(1.0f + __builtin_amdgcn_exp2f(-x));
}
__device__ __forceinline__ float tanh2(float y){   // y pre-scaled by 2*log2e
  float r = __builtin_amdgcn_rcpf(1.0f + __builtin_amdgcn_exp2f(y));
  return __builtin_fmaf(-2.0f, r, 1.0f);
}

// Fragment-contiguous PRE-SCALED weights + combined pre-scaled biases (block 511).
__global__ __launch_bounds__(256) void wprep_k(
    const float* Wz, const float* Wh,
    const float* Uzl,const float* Uzr,const float* Url,const float* Urr,
    const float* Uhl,const float* Uhr,
    const float* bWz,const float* bUzl,const float* bUzr,
    const float* bWr,const float* bUrl,const float* bUrr,
    const float* bWh,const float* bUhl,const float* bUhr,
    half_t* wb, float* bc){
  int idx = blockIdx.x*256 + threadIdx.x;           // 131072 total
  if (idx < 32768){                                  // Wz_f (x C1), Wh_f (x C2)
    const float* W = (idx < 16384) ? Wz : Wh;
    float sc = (idx < 16384) ? C1 : C2;
    int t = idx & 16383;
    int w = t >> 11, ks = (t >> 9) & 3, l = (t >> 3) & 63, j = t & 7;
    int n = w*16 + (l & 15);
    int k = ks*32 + ((l >> 4) << 3) + j;
    wb[idx] = (half_t)(W[k*128 + n] * sc);
  } else {                                           // Uz_f(C1), Ur_f(C1), Uh_f(C2)
    int t = idx - 32768;
    int mat = t >> 15;                               // 0=z,1=r,2=h
    t &= 32767;
    int w = t >> 12, ks = (t >> 9) & 7, l = (t >> 3) & 63, j = t & 7;
    int n = w*16 + (l & 15);
    int kp = ks*32 + ((l >> 4) << 3) + j;            // 0..255 interleaved
    int k = kp >> 1;
    const float* U;
    if (mat == 0) U = (kp & 1) ? Uzr : Uzl;
    else if (mat == 1) U = (kp & 1) ? Urr : Url;
    else U = (kp & 1) ? Uhr : Uhl;
    float sc = (mat == 2) ? C2 : C1;
    wb[idx] = (half_t)(U[k*128 + n] * sc);
  }
  if (blockIdx.x == 511 && threadIdx.x < 128){
    int j = threadIdx.x;
    bc[j]       = (bWz[j] + bUzl[j] + bUzr[j]) * C1;
    bc[128 + j] = (bWr[j] + bUrl[j] + bUrr[j]) * C1;
    bc[256 + j] = (bWh[j] + bUhl[j] + bUhr[j]) * C2;
  }
}

// Vocab table: t1[v] = (1-z)*tanh(...). Weights pre-scaled; sigm2/tanh2.
template<int MT>
__global__ __launch_bounds__(512, 8) void h1tab_k(
    const float* __restrict__ emb,
    const half_t* __restrict__ Wz_f, const half_t* __restrict__ Wh_f,
    const float* __restrict__ bc, half_t* __restrict__ t1)
{
  __shared__ __align__(16) _Float16 xs[MT*16][144];   // 72 dw === 8 mod 32
  const int tid = threadIdx.x;
  const int m0  = blockIdx.x*(MT*16);
  #pragma unroll
  for (int it = 0; it < MT; it++){
    int idx = it*512 + tid;
    int m = idx >> 5, c = idx & 31;
    int row = m0 + m; if (row >= NV) row = 0;
    float4 v = ((const float4*)(emb + (size_t)row*128))[c];
    union { half_t h[4]; ushort4 u; } p;
    p.h[0]=(half_t)v.x; p.h[1]=(half_t)v.y; p.h[2]=(half_t)v.z; p.h[3]=(half_t)v.w;
    *(ushort4*)&xs[m][c*4] = p.u;
  }
  __syncthreads();
  const int w = tid>>6, l = tid&63;
  const int lr = l&15, lk = (l>>4)*8, lq = (l>>4)*4;
  const int col = w*16 + lr;

  f32x4 zacc[MT] = {}; f32x4 hacc[MT] = {};
  const half_t* wzp = Wz_f + ((w*4)*64 + l)*8;
  const half_t* whp = Wh_f + ((w*4)*64 + l)*8;
  #pragma unroll
  for (int ks=0; ks<4; ks++){
    f16x8 bz = *(const f16x8*)(wzp + ks*512);
    f16x8 bh = *(const f16x8*)(whp + ks*512);
    #pragma unroll
    for (int mt=0; mt<MT; mt++){
      f16x8 a = *(const f16x8*)&xs[mt*16 + lr][ks*32 + lk];
      zacc[mt] = __builtin_amdgcn_mfma_f32_16x16x32_f16(a, bz, zacc[mt],0,0,0);
      hacc[mt] = __builtin_amdgcn_mfma_f32_16x16x32_f16(a, bh, hacc[mt],0,0,0);
    }
  }
  const float bzv = bc[col], bhv = bc[256+col];
  #pragma unroll
  for (int mt=0; mt<MT; mt++){
    #pragma unroll
    for (int q=0; q<4; q++){
      int row = m0 + mt*16 + lq + q;
      if (row < NV){
        float z  = sigm2(zacc[mt][q] + bzv);
        float ht = tanh2(hacc[mt][q] + bhv);
        t1[(size_t)row*128 + col] = (half_t)((1.f-z)*ht);
      }
    }
  }
}

// One tree level on LDS. X: input slots (interleaved {hl,hr}), Y: next-level input slots.
// RV = valid out rows (<= MT*16); slot0 = Y slot offset; LAST: write f32 to outf.
template<int MT, int RV, int LAST>
static __device__ __forceinline__ void level_step(
    _Float16 (*X)[LS], _Float16 (*Y)[LS], int tid,
    const half_t* Uz_f, const half_t* Ur_f, const half_t* Uh_f,
    const float* bc, float* outf, int outrow0, int slot0)
{
  const int w = tid>>6, l = tid&63;
  const int lr = l&15, lk = (l>>4)*8, lq = (l>>4)*4;
  const int col = w*16 + lr;

  f32x4 zacc[MT] = {}, racc[MT] = {};
  const half_t* uzp = Uz_f + ((w*8)*64 + l)*8;
  const half_t* urp = Ur_f + ((w*8)*64 + l)*8;
  #pragma unroll
  for (int ks=0; ks<8; ks++){
    f16x8 bz = *(const f16x8*)(uzp + ks*512);
    f16x8 br = *(const f16x8*)(urp + ks*512);
    #pragma unroll
    for (int mt=0; mt<MT; mt++){
      f16x8 a = *(const f16x8*)&X[mt*16 + lr][ks*32 + lk];
      zacc[mt] = __builtin_amdgcn_mfma_f32_16x16x32_f16(a, bz, zacc[mt],0,0,0);
      racc[mt] = __builtin_amdgcn_mfma_f32_16x16x32_f16(a, br, racc[mt],0,0,0);
    }
  }
  __syncthreads();

  uint zp[MT][2], sp[MT][2];
  const float bzv = bc[col], brv = bc[128+col];
  #pragma unroll
  for (int mt=0; mt<MT; mt++){
    union { half_t h[4]; uint u[2]; } pz, ps;
    #pragma unroll
    for (int q=0; q<4; q++){
      int row = mt*16 + lq + q;
      union { uint u; half_t h[2]; } io;
      io.u = *(uint*)&X[row][2*col];
      float hl = (float)io.h[0];
      float hr = (float)io.h[1];
      float z  = sigm2(zacc[mt][q] + bzv);
      float rv = sigm2(racc[mt][q] + brv);
      pz.h[q] = (half_t)z;
      ps.h[q] = (half_t)(hl + hr);
      io.h[0] = (half_t)(rv*hl);
      io.h[1] = (half_t)(rv*hr);
      *(uint*)&X[row][2*col] = io.u;
    }
    zp[mt][0]=pz.u[0]; zp[mt][1]=pz.u[1];
    sp[mt][0]=ps.u[0]; sp[mt][1]=ps.u[1];
  }
  __syncthreads();

  f32x4 ha[MT] = {};
  const half_t* uhp = Uh_f + ((w*8)*64 + l)*8;
  #pragma unroll
  for (int ks=0; ks<8; ks++){
    f16x8 bh = *(const f16x8*)(uhp + ks*512);
    #pragma unroll
    for (int mt=0; mt<MT; mt++){
      f16x8 a = *(const f16x8*)&X[mt*16 + lr][ks*32 + lk];
      ha[mt] = __builtin_amdgcn_mfma_f32_16x16x32_f16(a, bh, ha[mt],0,0,0);
    }
  }
  const float bhv = bc[256+col];
  #pragma unroll
  for (int mt=0; mt<MT; mt++){
    union { half_t h[4]; uint u[2]; } pz, ps;
    pz.u[0]=zp[mt][0]; pz.u[1]=zp[mt][1];
    ps.u[0]=sp[mt][0]; ps.u[1]=sp[mt][1];
    #pragma unroll
    for (int q=0; q<4; q++){
      int row = mt*16 + lq + q;
      if (row < RV){
        float ht = tanh2(ha[mt][q] + bhv);
        float z  = (float)pz.h[q];
        float o  = z*(float)ps.h[q] + (1.f-z)*ht;
        if (LAST) outf[(size_t)(outrow0 + row)*128 + col] = o;
        else      Y[slot0 + (row>>1)][2*col + (row&1)] = (half_t)o;
      }
    }
  }
  __syncthreads();
}

// Fused L1..L6: block g = batches 4g..4g+3 (tokens 256g..+255, L1 out rows 128g..+127).
// T14: chunk1's gather loads issued before chunk0's level_step; written after it.
__global__ __launch_bounds__(512, 2) void fused_k(
    const half_t* __restrict__ t1, const int* __restrict__ tokens,
    float* __restrict__ outf,
    const half_t* __restrict__ Uz_f, const half_t* __restrict__ Ur_f, const half_t* __restrict__ Uh_f,
    const float* __restrict__ bc)
{
  __shared__ __align__(16) _Float16 XA[64][LS];   // 34.8 KB
  __shared__ __align__(16) _Float16 XB[64][LS];   // 34.8 KB
  const int tid = threadIdx.x;
  const int g = blockIdx.x;

  uint2 sA[2][4], sB[2][4];
  auto gload = [&](int k){
    #pragma unroll
    for (int it = 0; it < 4; it++){
      int idx = it*512 + tid;           // 64 rows x 32 chunks
      int m = idx >> 5, c = idx & 31;
      int gm = 128*g + 64*k + m;        // global L1 out row
      int tl = tokens[2*gm], tr = tokens[2*gm+1];
      sA[k][it] = *(const uint2*)(t1 + (size_t)tl*128 + c*4);
      sB[k][it] = *(const uint2*)(t1 + (size_t)tr*128 + c*4);
    }
  };
  auto gwrite = [&](int k){
    #pragma unroll
    for (int it = 0; it < 4; it++){
      int idx = it*512 + tid;
      int m = idx >> 5, c = idx & 31;
      uint2 A = sA[k][it], Bv = sB[k][it];
      uint4 o;
      o.x = (A.x & 0xFFFFu) | (Bv.x << 16);
      o.y = (A.x >> 16)     | (Bv.x & 0xFFFF0000u);
      o.z = (A.y & 0xFFFFu) | (Bv.y << 16);
      o.w = (A.y >> 16)     | (Bv.y & 0xFFFF0000u);
      *(uint4*)&XA[m][c*8] = o;
    }
  };

  // ---- L1, two chunks; chunk1 loads in flight during chunk0's level_step ----
  gload(0);
  gwrite(0);
  gload(1);                     // T14: issue now, consume after chunk0
  __syncthreads();
  level_step<4,64,0>(XA, XB, tid, Uz_f, Ur_f, Uh_f, bc, outf, 0, 0);   // chunk0 -> XB 0..31
  gwrite(1);                    // XA free after level_step's trailing sync
  __syncthreads();
  level_step<4,64,0>(XA, XB, tid, Uz_f, Ur_f, Uh_f, bc, outf, 0, 32);  // chunk1 -> XB 32..63

  // ---- L2..L6 in LDS ----
  level_step<4,64,0>(XB, XA, tid, Uz_f, Ur_f, Uh_f, bc, outf, 0, 0);   // L2: 64 out -> XA 0..31
  level_step<2,32,0>(XA, XB, tid, Uz_f, Ur_f, Uh_f, bc, outf, 0, 0);   // L3: 32 out -> XB 0..15
  level_step<1,16,0>(XB, XA, tid, Uz_f, Ur_f, Uh_f, bc, outf, 0, 0);   // L4: 16 out -> XA 0..7
  level_step<1, 8,0>(XA, XB, tid, Uz_f, Ur_f, Uh_f, bc, outf, 0, 0);   // L5:  8 out -> XB 0..3
  level_step<1, 4,1>(XB, XA, tid, Uz_f, Ur_f, Uh_f, bc, outf, 4*g, 0); // L6:  4 out -> f32
}

extern "C" void kernel_launch(void* const* d_in, const int* in_sizes, int n_in,
                              void* d_out, int out_size, void* d_ws, size_t ws_size,
                              hipStream_t stream) {
  const int*   tokens = (const int*)  d_in[0];
  const float* emb    = (const float*)d_in[1];
  const float* Wz  = (const float*)d_in[2];  const float* bWz  = (const float*)d_in[3];
  const float* Uzl = (const float*)d_in[4];  const float* bUzl = (const float*)d_in[5];
  const float* Uzr = (const float*)d_in[6];  const float* bUzr = (const float*)d_in[7];
  const float* Wr  = (const float*)d_in[8];  const float* bWr  = (const float*)d_in[9];
  const float* Url = (const float*)d_in[10]; const float* bUrl = (const float*)d_in[11];
  const float* Urr = (const float*)d_in[12]; const float* bUrr = (const float*)d_in[13];
  const float* Wh  = (const float*)d_in[14]; const float* bWh  = (const float*)d_in[15];
  const float* Uhl = (const float*)d_in[16]; const float* bUhl = (const float*)d_in[17];
  const float* Uhr = (const float*)d_in[18]; const float* bUhr = (const float*)d_in[19];

  float*  bc = (float*)d_ws;
  half_t* wb = (half_t*)((char*)d_ws + 4096);
  half_t* Wz_f = wb;
  half_t* Wh_f = wb + 16384;
  half_t* Uz_f = wb + 32768;
  half_t* Ur_f = wb + 65536;
  half_t* Uh_f = wb + 98304;
  half_t* t1 = (half_t*)((char*)d_ws + (1<<20));     // 100000*128 f16 = 25.6 MB

  wprep_k<<<512, 256, 0, stream>>>(Wz,Wh,Uzl,Uzr,Url,Urr,Uhl,Uhr,
                                   bWz,bUzl,bUzr,bWr,bUrl,bUrr,bWh,bUhl,bUhr, wb, bc);

  h1tab_k<4><<<(NV + 63)/64, 512, 0, stream>>>(emb, Wz_f, Wh_f, bc, t1);

  // All 6 tree levels fused: 1024 blocks x 4 batches
  fused_k<<<1024, 512, 0, stream>>>(t1, tokens, (float*)d_out, Uz_f, Ur_f, Uh_f, bc);
}